// Round 4
// baseline (148.275 us; speedup 1.0000x reference)
//
#include <hip/hip_runtime.h>

// Haar wavelet transform, single fused pass.
// x: (8, 64, 512, 512) f32 -> low, high: (8, 64, 256, 256) f32 each.
// low  = 0.5*(a+b+c+d)
// high = lh+hl+hh = 0.5*(3d - a - b - c)
// where a=x[2i,2j], b=x[2i,2j+1], c=x[2i+1,2j], d=x[2i+1,2j+1].
//
// One item = 4 output pixels: thread reads 2x 32B (two 16B vectors per input
// row), writes one 16B vector to low and one to high.
// Loads are REGULAR (cached): the per-instruction pattern is 16B/lane at 32B
// stride, so L1/L2 must merge the two half-line accesses -- nt loads defeat
// that merge (suspected partial-line HBM refetch). Stores stay nt (write-once
// streams, keep them out of L2).
// Grid-stride = 2^19 items only advances the plane bits (jq, i invariant per
// thread), so the decode is hoisted and the loop is pure pointer bumps.

typedef float f32x4 __attribute__((ext_vector_type(4)));

__global__ __launch_bounds__(256) void haar_kernel(
    const float* __restrict__ x,
    float* __restrict__ low,
    float* __restrict__ high,
    unsigned n_items)  // planes * 256 rows * 64 col-quads = 2^23
{
    const unsigned idx0 = blockIdx.x * blockDim.x + threadIdx.x;
    const unsigned stride = gridDim.x * blockDim.x;   // 2^19: only plane bits advance

    // Invariant decode (valid for every idx = idx0 + k*stride since stride >= 2^14).
    const unsigned jq = idx0 & 63u;          // col quad (out cols 4jq..4jq+3)
    const unsigned i  = (idx0 >> 6) & 255u;  // out row

    const unsigned in_off  = (2u * i) * 512u + 8u * jq;  // within-plane input offset
    const unsigned out_off = i * 256u + 4u * jq;         // within-plane output offset

    // Per-iteration plane advance: stride items = stride>>14 planes.
    const unsigned in_step  = (stride >> 14) * 262144u;
    const unsigned out_step = (stride >> 14) * 65536u;

    const float* xin = x   + (idx0 >> 14) * 262144u + in_off;
    float* plo = low  + (idx0 >> 14) * 65536u + out_off;
    float* phi = high + (idx0 >> 14) * 65536u + out_off;

    for (unsigned idx = idx0; idx < n_items; idx += stride) {
        const f32x4* r0 = reinterpret_cast<const f32x4*>(xin);         // row 2i
        const f32x4* r1 = reinterpret_cast<const f32x4*>(xin + 512u);  // row 2i+1
        const f32x4 v00 = r0[0];  // a0 b0 a1 b1
        const f32x4 v01 = r0[1];  // a2 b2 a3 b3
        const f32x4 v10 = r1[0];  // c0 d0 c1 d1
        const f32x4 v11 = r1[1];  // c2 d2 c3 d3

        f32x4 lo, hi;
        lo.x = 0.5f * (v00.x + v00.y + v10.x + v10.y);
        hi.x = 0.5f * (3.0f * v10.y - v00.x - v00.y - v10.x);
        lo.y = 0.5f * (v00.z + v00.w + v10.z + v10.w);
        hi.y = 0.5f * (3.0f * v10.w - v00.z - v00.w - v10.z);
        lo.z = 0.5f * (v01.x + v01.y + v11.x + v11.y);
        hi.z = 0.5f * (3.0f * v11.y - v01.x - v01.y - v11.x);
        lo.w = 0.5f * (v01.z + v01.w + v11.z + v11.w);
        hi.w = 0.5f * (3.0f * v11.w - v01.z - v01.w - v11.z);

        __builtin_nontemporal_store(lo, reinterpret_cast<f32x4*>(plo));
        __builtin_nontemporal_store(hi, reinterpret_cast<f32x4*>(phi));

        xin += in_step;
        plo += out_step;
        phi += out_step;
    }
}

extern "C" void kernel_launch(void* const* d_in, const int* in_sizes, int n_in,
                              void* d_out, int out_size, void* d_ws, size_t ws_size,
                              hipStream_t stream) {
    const float* x = (const float*)d_in[0];
    float* out = (float*)d_out;

    // out_size = 2 * 8*64*256*256 = 67,108,864 ; low first, then high.
    const unsigned half = (unsigned)(out_size / 2);   // 33,554,432
    float* low  = out;
    float* high = out + half;

    const unsigned n_items = half / 4;                // one item = 4 output pixels
    const int block = 256;
    const int grid = 2048;                            // 8 blocks/CU, grid-stride

    haar_kernel<<<grid, block, 0, stream>>>(x, low, high, n_items);
}

// Round 5
// 134.746 us; speedup vs baseline: 1.1004x; 1.1004x over previous
//
#include <hip/hip_runtime.h>

// Haar wavelet transform, single fused pass, wave-per-row-pair layout.
// x: (8, 64, 512, 512) f32 -> low, high: (8, 64, 256, 256) f32 each.
// low  = 0.5*(a+b+c+d) ; high = 0.5*(3d - a - b - c)
// a=x[2i,2j], b=x[2i,2j+1], c=x[2i+1,2j], d=x[2i+1,2j+1].
//
// One WAVE owns one input row-pair (2 x 2KB) -> one output row (2 x 1KB).
// Lane t loads f4 elements {t, t+64} of each input row: every load
// instruction is 16B/lane FULLY CONTIGUOUS across the wave (1KB span).
// f4 #k yields output pixel pair (2k, 2k+1), so lane t's pixels are
// (2t,2t+1) [A] and (128+2t,128+2t+1) [B] -- non-contiguous. A 16-shfl
// cross-lane exchange regroups so lane t stores pixels 4t..4t+3 as one
// 16B nt-store per output stream (also fully contiguous).
//   dest lane t<32 : A-pairs of src lanes 2t, 2t+1
//   dest lane t>=32: B-pairs of src lanes 2(t-32), 2(t-32)+1
// All traffic nt (touch-once streams). VALUBusy was 5% -> shuffles are free.

typedef float f32x4 __attribute__((ext_vector_type(4)));

__global__ __launch_bounds__(256) void haar_kernel(
    const float* __restrict__ x,
    float* __restrict__ low,
    float* __restrict__ high)
{
    const unsigned lane = threadIdx.x & 63u;
    const unsigned wid  = (blockIdx.x << 2) | (threadIdx.x >> 6);  // 0..131071
    const unsigned p = wid >> 8;      // plane (b*64 + c), 0..511
    const unsigned i = wid & 255u;    // output row, 0..255

    const float* row0 = x + p * 262144u + (2u * i) * 512u;
    const f32x4* r0 = reinterpret_cast<const f32x4*>(row0);         // row 2i
    const f32x4* r1 = reinterpret_cast<const f32x4*>(row0 + 512);   // row 2i+1

    const f32x4 va0 = __builtin_nontemporal_load(r0 + lane);        // cols 4t..4t+3
    const f32x4 va1 = __builtin_nontemporal_load(r0 + 64 + lane);   // cols 256+4t..
    const f32x4 vb0 = __builtin_nontemporal_load(r1 + lane);
    const f32x4 vb1 = __builtin_nontemporal_load(r1 + 64 + lane);

    // A: pixel pair (2t, 2t+1); B: pixel pair (128+2t, 128+2t+1)
    const float loA0 = 0.5f * (va0.x + va0.y + vb0.x + vb0.y);
    const float hiA0 = 0.5f * (3.0f * vb0.y - va0.x - va0.y - vb0.x);
    const float loA1 = 0.5f * (va0.z + va0.w + vb0.z + vb0.w);
    const float hiA1 = 0.5f * (3.0f * vb0.w - va0.z - va0.w - vb0.z);
    const float loB0 = 0.5f * (va1.x + va1.y + vb1.x + vb1.y);
    const float hiB0 = 0.5f * (3.0f * vb1.y - va1.x - va1.y - vb1.x);
    const float loB1 = 0.5f * (va1.z + va1.w + vb1.z + vb1.w);
    const float hiB1 = 0.5f * (3.0f * vb1.w - va1.z - va1.w - vb1.z);

    const int s0 = (int)((2u * lane) & 63u);
    const int s1 = s0 + 1;
    const bool first = lane < 32u;

    f32x4 lo4, hi4;
    { const float a = __shfl(loA0, s0), b = __shfl(loB0, s0); lo4.x = first ? a : b; }
    { const float a = __shfl(loA1, s0), b = __shfl(loB1, s0); lo4.y = first ? a : b; }
    { const float a = __shfl(loA0, s1), b = __shfl(loB0, s1); lo4.z = first ? a : b; }
    { const float a = __shfl(loA1, s1), b = __shfl(loB1, s1); lo4.w = first ? a : b; }
    { const float a = __shfl(hiA0, s0), b = __shfl(hiB0, s0); hi4.x = first ? a : b; }
    { const float a = __shfl(hiA1, s0), b = __shfl(hiB1, s0); hi4.y = first ? a : b; }
    { const float a = __shfl(hiA0, s1), b = __shfl(hiB0, s1); hi4.z = first ? a : b; }
    { const float a = __shfl(hiA1, s1), b = __shfl(hiB1, s1); hi4.w = first ? a : b; }

    const unsigned obase = p * 65536u + i * 256u + 4u * lane;
    __builtin_nontemporal_store(lo4, reinterpret_cast<f32x4*>(low + obase));
    __builtin_nontemporal_store(hi4, reinterpret_cast<f32x4*>(high + obase));
}

extern "C" void kernel_launch(void* const* d_in, const int* in_sizes, int n_in,
                              void* d_out, int out_size, void* d_ws, size_t ws_size,
                              hipStream_t stream) {
    const float* x = (const float*)d_in[0];
    float* out = (float*)d_out;

    // out_size = 2 * 8*64*256*256 = 67,108,864 ; low first, then high.
    const unsigned half = (unsigned)(out_size / 2);   // 33,554,432
    float* low  = out;
    float* high = out + half;

    // 512 planes * 256 output rows = 131072 waves; 4 waves/block -> 32768 blocks.
    const int block = 256;
    const int grid = 32768;

    haar_kernel<<<grid, block, 0, stream>>>(x, low, high);
}